// Round 3
// baseline (30.214 us; speedup 1.0000x reference)
//
#include <hip/hip_runtime.h>
#include <math.h>

#define BB 512

// One wave (64 threads) per anchor row j; lane owns columns {lane + 64u}.
// Last-arriving block folds the 512 row partials into the scalar output.
__global__ __launch_bounds__(64) void tshl_kernel(
    const float* __restrict__ pdist, const int* __restrict__ target,
    float* __restrict__ row_sum, float* __restrict__ row_cnt,
    unsigned int* __restrict__ counter, float* __restrict__ out)
{
    const int j    = blockIdx.x;
    const int lane = threadIdx.x;

    const int myLab = target[j];

    float d[8];
    int   lab[8];
    #pragma unroll
    for (int u = 0; u < 8; ++u) {
        const int c = lane + 64 * u;
        d[u]   = pdist[j * BB + c];
        lab[u] = target[c];
    }

    bool neg[8], pos[8];
    float lmax = -INFINITY, lmin = INFINITY;
    #pragma unroll
    for (int u = 0; u < 8; ++u) {
        neg[u] = (lab[u] != myLab);
        pos[u] = (!neg[u]) && (lane + 64 * u != j);
        lmin = fminf(lmin, d[u]);
        if (neg[u]) lmax = fmaxf(lmax, d[u]);
    }
    #pragma unroll
    for (int m = 32; m; m >>= 1) {
        lmax = fmaxf(lmax, __shfl_xor(lmax, m));
        lmin = fminf(lmin, __shfl_xor(lmin, m));
    }
    // masked_maximum fallback: if no unequal label in row, falls back to row min.
    const float neg_in = (lmax == -INFINITY) ? lmin : lmax;

    // Per-positive semi-hard negative: min{d[k] : neg[k] && d[k] > dpos}.
    float psum = 0.0f;   // lane-replicated (identical on all lanes)
    int   npos = 0;
    #pragma unroll
    for (int u = 0; u < 8; ++u) {
        unsigned long long bal = __ballot(pos[u]);
        npos += __popcll(bal);
        while (bal) {
            const int src = __builtin_ctzll(bal);
            bal &= bal - 1;
            const float dpos = __shfl(d[u], src);
            float c = INFINITY;
            #pragma unroll
            for (int v = 0; v < 8; ++v)
                if (neg[v] && d[v] > dpos) c = fminf(c, d[v]);
            #pragma unroll
            for (int m = 32; m; m >>= 1) c = fminf(c, __shfl_xor(c, m));
            const float shn = (c < INFINITY) ? c : neg_in;
            psum += fmaxf(1.0f + dpos - shn, 0.0f);
        }
    }

    // Publish row partials at agent (device) scope so the last block sees them
    // across non-coherent per-XCD L2s.
    if (lane == 0) {
        __hip_atomic_store(&row_sum[j], psum, __ATOMIC_RELAXED,
                           __HIP_MEMORY_SCOPE_AGENT);
        __hip_atomic_store(&row_cnt[j], (float)npos, __ATOMIC_RELAXED,
                           __HIP_MEMORY_SCOPE_AGENT);
    }
    __threadfence();   // release: partials reach device coherence point

    unsigned int old = 0;
    if (lane == 0)
        old = __hip_atomic_fetch_add(counter, 1u, __ATOMIC_ACQ_REL,
                                     __HIP_MEMORY_SCOPE_AGENT);
    old = __shfl(old, 0);

    // Modular fire condition: exactly one block per launch sees this, for ANY
    // persisted starting value of *counter (0xAAAAAAAA poison, replay carry-over).
    if ((old & (BB - 1)) == (BB - 1)) {
        __threadfence();   // acquire: see all other blocks' partials
        float s = 0.0f, cn = 0.0f;
        #pragma unroll
        for (int u = 0; u < 8; ++u) {
            const int r = lane + 64 * u;
            s  += __hip_atomic_load(&row_sum[r], __ATOMIC_RELAXED,
                                    __HIP_MEMORY_SCOPE_AGENT);
            cn += __hip_atomic_load(&row_cnt[r], __ATOMIC_RELAXED,
                                    __HIP_MEMORY_SCOPE_AGENT);
        }
        #pragma unroll
        for (int m = 32; m; m >>= 1) {
            s  += __shfl_xor(s, m);
            cn += __shfl_xor(cn, m);
        }
        if (lane == 0) out[0] = s / fmaxf(cn, 1.0f);
    }
}

extern "C" void kernel_launch(void* const* d_in, const int* in_sizes, int n_in,
                              void* d_out, int out_size, void* d_ws, size_t ws_size,
                              hipStream_t stream) {
    const float* pdist  = (const float*)d_in[0];
    const int*   target = (const int*)d_in[1];
    float* ws           = (float*)d_ws;
    float* row_sum      = ws;                       // [512]
    float* row_cnt      = ws + BB;                  // [512]
    unsigned int* counter = (unsigned int*)(ws + 2 * BB);
    float* out          = (float*)d_out;

    tshl_kernel<<<BB, 64, 0, stream>>>(pdist, target, row_sum, row_cnt,
                                       counter, out);
}

// Round 4
// 13.368 us; speedup vs baseline: 2.2602x; 2.2602x over previous
//
#include <hip/hip_runtime.h>
#include <math.h>

#define BB 512

// 4 rows per 256-thread block, one wave per row. No LDS, no barriers.
// Lane owns 8 contiguous columns -> 2x float4 / 2x int4 vector loads.
__global__ __launch_bounds__(256) void tshl_row_kernel(
    const float* __restrict__ pdist, const int* __restrict__ target,
    float* __restrict__ row_sum, float* __restrict__ row_cnt)
{
    const int lane = threadIdx.x & 63;
    const int w    = threadIdx.x >> 6;
    const int j    = (blockIdx.x << 2) + w;

    const int base = lane << 3;           // 8 columns per lane, contiguous
    const float4 p0 = *(const float4*)(pdist + j * BB + base);
    const float4 p1 = *(const float4*)(pdist + j * BB + base + 4);
    const int4   t0 = *(const int4*)(target + base);
    const int4   t1 = *(const int4*)(target + base + 4);
    const int myLab = target[j];

    const float d[8]   = {p0.x, p0.y, p0.z, p0.w, p1.x, p1.y, p1.z, p1.w};
    const int   lab[8] = {t0.x, t0.y, t0.z, t0.w, t1.x, t1.y, t1.z, t1.w};

    bool neg[8], pos[8];
    float lmax = -INFINITY, lmin = INFINITY;
    #pragma unroll
    for (int u = 0; u < 8; ++u) {
        neg[u] = (lab[u] != myLab);
        pos[u] = (!neg[u]) && (base + u != j);
        lmin = fminf(lmin, d[u]);
        if (neg[u]) lmax = fmaxf(lmax, d[u]);
    }
    #pragma unroll
    for (int m = 32; m; m >>= 1) {
        lmax = fmaxf(lmax, __shfl_xor(lmax, m));
        lmin = fminf(lmin, __shfl_xor(lmin, m));
    }
    // masked_maximum fallback: no unequal label in row -> row min.
    const float neg_in = (lmax == -INFINITY) ? lmin : lmax;

    // Per positive i: shn = min{d[k] : label[k]!=myLab && d[k] > d[i]},
    // fallback neg_in. Iterate positives via ballot/ctz (register-only).
    float psum = 0.0f;
    int   npos = 0;
    #pragma unroll
    for (int u = 0; u < 8; ++u) {
        unsigned long long bal = __ballot(pos[u]);
        npos += __popcll(bal);
        while (bal) {
            const int src = __builtin_ctzll(bal);
            bal &= bal - 1;
            const float dpos = __shfl(d[u], src);
            float c = INFINITY;
            #pragma unroll
            for (int v = 0; v < 8; ++v)
                if (neg[v] && d[v] > dpos) c = fminf(c, d[v]);
            #pragma unroll
            for (int m = 32; m; m >>= 1) c = fminf(c, __shfl_xor(c, m));
            const float shn = (c < INFINITY) ? c : neg_in;
            psum += fmaxf(1.0f + dpos - shn, 0.0f);
        }
    }

    if (lane == 0) {
        row_sum[j] = psum;
        row_cnt[j] = (float)npos;
    }
}

// Single-wave final reduce: out = sum / max(cnt, 1).
__global__ __launch_bounds__(64) void tshl_final_kernel(
    const float* __restrict__ row_sum, const float* __restrict__ row_cnt,
    float* __restrict__ out)
{
    const int lane = threadIdx.x;
    const int base = lane << 3;
    const float4 s0 = *(const float4*)(row_sum + base);
    const float4 s1 = *(const float4*)(row_sum + base + 4);
    const float4 c0 = *(const float4*)(row_cnt + base);
    const float4 c1 = *(const float4*)(row_cnt + base + 4);
    float s = ((s0.x + s0.y) + (s0.z + s0.w)) + ((s1.x + s1.y) + (s1.z + s1.w));
    float c = ((c0.x + c0.y) + (c0.z + c0.w)) + ((c1.x + c1.y) + (c1.z + c1.w));
    #pragma unroll
    for (int m = 32; m; m >>= 1) {
        s += __shfl_xor(s, m);
        c += __shfl_xor(c, m);
    }
    if (lane == 0) out[0] = s / fmaxf(c, 1.0f);
}

extern "C" void kernel_launch(void* const* d_in, const int* in_sizes, int n_in,
                              void* d_out, int out_size, void* d_ws, size_t ws_size,
                              hipStream_t stream) {
    const float* pdist  = (const float*)d_in[0];
    const int*   target = (const int*)d_in[1];
    float* ws      = (float*)d_ws;
    float* row_sum = ws;          // [512]
    float* row_cnt = ws + BB;     // [512]
    float* out     = (float*)d_out;

    tshl_row_kernel<<<BB / 4, 256, 0, stream>>>(pdist, target, row_sum, row_cnt);
    tshl_final_kernel<<<1, 64, 0, stream>>>(row_sum, row_cnt, out);
}

// Round 5
// 12.884 us; speedup vs baseline: 2.3452x; 1.0376x over previous
//
#include <hip/hip_runtime.h>
#include <math.h>

#define BB   512
#define NBLK 64     // blocks; 8 waves each -> one wave per row
#define TPB  512

// Single dispatch. 64 blocks x 8 waves; wave w of block b owns row j = 8b+w.
// Lane owns 8 contiguous columns (2x float4 + 2x int4). Block reduces its 8
// rows in LDS, publishes one partial pair at agent scope, arrives on a
// counter; the block whose arrival index == 63 (mod 64) folds 64 partials.
__global__ __launch_bounds__(TPB) void tshl_kernel(
    const float* __restrict__ pdist, const int* __restrict__ target,
    float* __restrict__ part_sum, float* __restrict__ part_cnt,
    unsigned int* __restrict__ counter, float* __restrict__ out)
{
    const int lane = threadIdx.x & 63;
    const int w    = threadIdx.x >> 6;
    const int j    = (blockIdx.x << 3) + w;

    const int base = lane << 3;
    const float4 p0 = *(const float4*)(pdist + j * BB + base);
    const float4 p1 = *(const float4*)(pdist + j * BB + base + 4);
    const int4   t0 = *(const int4*)(target + base);
    const int4   t1 = *(const int4*)(target + base + 4);
    const int myLab = target[j];

    const float d[8]   = {p0.x, p0.y, p0.z, p0.w, p1.x, p1.y, p1.z, p1.w};
    const int   lab[8] = {t0.x, t0.y, t0.z, t0.w, t1.x, t1.y, t1.z, t1.w};

    bool neg[8], pos[8];
    float lmax = -INFINITY, lmin = INFINITY;
    #pragma unroll
    for (int u = 0; u < 8; ++u) {
        neg[u] = (lab[u] != myLab);
        pos[u] = (!neg[u]) && (base + u != j);
        lmin = fminf(lmin, d[u]);
        if (neg[u]) lmax = fmaxf(lmax, d[u]);
    }
    #pragma unroll
    for (int m = 32; m; m >>= 1) {
        lmax = fmaxf(lmax, __shfl_xor(lmax, m));
        lmin = fminf(lmin, __shfl_xor(lmin, m));
    }
    // masked_maximum fallback: no unequal label in row -> row min.
    const float neg_in = (lmax == -INFINITY) ? lmin : lmax;

    // Per positive i: shn = min{d[k] : neg[k] && d[k] > d[i]}, else neg_in.
    float psum = 0.0f;   // lane-uniform after each butterfly
    int   npos = 0;
    #pragma unroll
    for (int u = 0; u < 8; ++u) {
        unsigned long long bal = __ballot(pos[u]);
        npos += __popcll(bal);
        while (bal) {
            const int src = __builtin_ctzll(bal);
            bal &= bal - 1;
            const float dpos = __shfl(d[u], src);
            float c = INFINITY;
            #pragma unroll
            for (int v = 0; v < 8; ++v)
                if (neg[v] && d[v] > dpos) c = fminf(c, d[v]);
            #pragma unroll
            for (int m = 32; m; m >>= 1) c = fminf(c, __shfl_xor(c, m));
            const float shn = (c < INFINITY) ? c : neg_in;
            psum += fmaxf(1.0f + dpos - shn, 0.0f);
        }
    }

    // Block-level reduce of the 8 row results (fixed order -> deterministic).
    __shared__ float ssum[8], scnt[8];
    if (lane == 0) { ssum[w] = psum; scnt[w] = (float)npos; }
    __syncthreads();

    unsigned int old = 0;
    if (threadIdx.x == 0) {
        float bs = 0.0f, bc = 0.0f;
        #pragma unroll
        for (int e = 0; e < 8; ++e) { bs += ssum[e]; bc += scnt[e]; }
        __hip_atomic_store(&part_sum[blockIdx.x], bs, __ATOMIC_RELAXED,
                           __HIP_MEMORY_SCOPE_AGENT);
        __hip_atomic_store(&part_cnt[blockIdx.x], bc, __ATOMIC_RELAXED,
                           __HIP_MEMORY_SCOPE_AGENT);
        __threadfence();   // release: partials reach device coherence point
        old = __hip_atomic_fetch_add(counter, 1u, __ATOMIC_RELEASE,
                                     __HIP_MEMORY_SCOPE_AGENT);
    }

    if (w == 0) {
        old = __shfl(old, 0);
        // Exactly one block per launch fires, for ANY persisted counter value.
        if ((old & (NBLK - 1)) == (NBLK - 1)) {
            __threadfence();   // acquire: see all other blocks' partials
            float s = 0.0f, c = 0.0f;
            if (lane < NBLK) {
                s = __hip_atomic_load(&part_sum[lane], __ATOMIC_RELAXED,
                                      __HIP_MEMORY_SCOPE_AGENT);
                c = __hip_atomic_load(&part_cnt[lane], __ATOMIC_RELAXED,
                                      __HIP_MEMORY_SCOPE_AGENT);
            }
            #pragma unroll
            for (int m = 32; m; m >>= 1) {
                s += __shfl_xor(s, m);
                c += __shfl_xor(c, m);
            }
            if (lane == 0) out[0] = s / fmaxf(c, 1.0f);
        }
    }
}

extern "C" void kernel_launch(void* const* d_in, const int* in_sizes, int n_in,
                              void* d_out, int out_size, void* d_ws, size_t ws_size,
                              hipStream_t stream) {
    const float* pdist  = (const float*)d_in[0];
    const int*   target = (const int*)d_in[1];
    float* ws             = (float*)d_ws;
    float* part_sum       = ws;                 // [64]
    float* part_cnt       = ws + NBLK;          // [64]
    unsigned int* counter = (unsigned int*)(ws + 2 * NBLK);
    float* out            = (float*)d_out;

    tshl_kernel<<<NBLK, TPB, 0, stream>>>(pdist, target, part_sum, part_cnt,
                                          counter, out);
}